// Round 11
// baseline (229.243 us; speedup 1.0000x reference)
//
#include <hip/hip_runtime.h>
#include <math.h>

typedef unsigned short u16;
typedef unsigned int u32;
typedef __attribute__((ext_vector_type(4))) float f32x4;
typedef __attribute__((ext_vector_type(8))) short bf16x8;

#define NP 16
#define DLAT 768
#define HDIM 3072
#define NB 256
#define MAXO 250
#define TOT 2800

__device__ __forceinline__ u16 f2b(float f) {
  union { float f; u32 u; } v; v.f = f;
  u32 u = v.u;
  u32 r = (u + 0x7fffu + ((u >> 16) & 1u)) >> 16;
  return (u16)r;
}

__device__ __forceinline__ u32 cvtpk(float lo, float hi) {
  u32 r;
  asm("v_cvt_pk_bf16_f32 %0, %1, %2" : "=v"(r) : "v"(lo), "v"(hi));
  return r;
}

__device__ __forceinline__ void gll16(const void* g, void* l) {
  __builtin_amdgcn_global_load_lds(
      (const __attribute__((address_space(1))) void*)g,
      (__attribute__((address_space(3))) void*)l, 16, 0, 0);
}

// ---------------- LayerNorm: x[B,P,D] fp32 -> xn[P,B,D] bf16 ----------------
__global__ __launch_bounds__(256) void ln_kernel(
    const float* __restrict__ x, const float* __restrict__ gamma,
    const float* __restrict__ beta, u16* __restrict__ xn) {
  const int wave = threadIdx.x >> 6, lane = threadIdx.x & 63;
  const int row = blockIdx.x * 4 + wave;
  const int b = row >> 4, p = row & 15;
  const float4* xr = (const float4*)(x + (size_t)row * DLAT);
  const float4* g4 = (const float4*)(gamma + (size_t)p * DLAT);
  const float4* b4 = (const float4*)(beta + (size_t)p * DLAT);
  float4 v[3];
  float s = 0.f, ss = 0.f;
#pragma unroll
  for (int j = 0; j < 3; ++j) {
    v[j] = xr[lane + j * 64];
    s += v[j].x + v[j].y + v[j].z + v[j].w;
    ss += v[j].x * v[j].x + v[j].y * v[j].y + v[j].z * v[j].z + v[j].w * v[j].w;
  }
#pragma unroll
  for (int o = 32; o; o >>= 1) { s += __shfl_xor(s, o); ss += __shfl_xor(ss, o); }
  const float mu = s * (1.f / 768.f);
  const float var = ss * (1.f / 768.f) - mu * mu;
  const float rstd = rsqrtf(var + 1e-5f);
  u16* xo = xn + ((size_t)(p * NB + b)) * DLAT;
#pragma unroll
  for (int j = 0; j < 3; ++j) {
    const int f = lane + j * 64;
    float4 g = g4[f], be = b4[f];
    float o0 = (v[j].x - mu) * rstd * g.x + be.x;
    float o1 = (v[j].y - mu) * rstd * g.y + be.y;
    float o2 = (v[j].z - mu) * rstd * g.z + be.z;
    float o3 = (v[j].w - mu) * rstd * g.w + be.w;
    uint2 w;
    w.x = (u32)f2b(o0) | ((u32)f2b(o1) << 16);
    w.y = (u32)f2b(o2) | ((u32)f2b(o3) << 16);
    *(uint2*)&xo[f * 4] = w;
  }
}

// ===================== PROBES (write to scratch; h is overwritten later) ====
// Common geometry: 768 blocks = 16p x 2mt x 24nt, BM=128, BN=128, 4 waves 2x2.

#define PDECODE \
  const int bid = blockIdx.x; \
  const int p = bid / 48; \
  const int rem = bid % 48; \
  const int m0 = (rem / 24) * 128; \
  const int n0 = (rem % 24) * 128; \
  const int tid = threadIdx.x; \
  const int lane = tid & 63, wave = tid >> 6; \
  const int lanelo = lane & 15, lanehi = lane >> 4; \
  const int wr = wave >> 1, wc = wave & 1; \
  const u16* Ap = xn + (size_t)p * NB * DLAT + (size_t)m0 * DLAT; \
  const float* Bp = w1 + (size_t)p * HDIM * DLAT + (size_t)n0 * DLAT;

// ---- p1: stage-only, BK=64, single buffer, syncthreads drain per chunk ----
__global__ __launch_bounds__(256) void p1_stage(
    const u16* __restrict__ xn, const float* __restrict__ w1, float* __restrict__ scr) {
  PDECODE
  __shared__ u16 As[128 * 64];
  __shared__ float Bs[128 * 64];
  int a_src[4], b_src[8];
#pragma unroll
  for (int j = 0; j < 4; ++j) {
    const int s = tid + 256 * j, r = s >> 3, c = s & 7;
    a_src[j] = r * DLAT + ((c ^ (r & 7)) << 3);
  }
#pragma unroll
  for (int j = 0; j < 8; ++j) {
    const int s = tid + 256 * j, r = s >> 4, c = s & 15;
    b_src[j] = r * DLAT + ((c ^ (r & 7)) << 2);
  }
  for (int ch = 0; ch < 12; ++ch) {
    const int k2 = ch * 64;
#pragma unroll
    for (int j = 0; j < 4; ++j) gll16(Ap + a_src[j] + k2, &As[(tid + 256 * j) * 8]);
#pragma unroll
    for (int j = 0; j < 8; ++j) gll16(Bp + b_src[j] + k2, &Bs[(tid + 256 * j) * 4]);
    __syncthreads();
  }
  scr[bid * 256 + tid] = (float)As[tid * 8] + Bs[tid * 4];
}

// ---- p2: compute-only, BK=64 x 12 chunks, barriers, no memory traffic ----
__global__ __launch_bounds__(256) void p2_comp(
    const u16* __restrict__ xn, const float* __restrict__ w1, float* __restrict__ scr) {
  PDECODE
  (void)Ap; (void)Bp;
  __shared__ u16 As[128 * 64];
  __shared__ float Bs[128 * 64];
#pragma unroll
  for (int j = 0; j < 2; ++j) *(uint4*)&As[tid * 16 + j * 8] = uint4{0, 0, 0, 0};
#pragma unroll
  for (int j = 0; j < 8; ++j) *(float4*)&Bs[tid * 32 + j * 4] = float4{0.f, 0.f, 0.f, 0.f};
  __syncthreads();
  f32x4 acc[4][4] = {};
  for (int ch = 0; ch < 12; ++ch) {
    __syncthreads();
#pragma unroll
    for (int kt = 0; kt < 2; ++kt) {
      bf16x8 af[4], bf[4];
#pragma unroll
      for (int m = 0; m < 4; ++m) {
        const int ra = wr * 64 + m * 16 + lanelo;
        af[m] = *(const bf16x8*)&As[ra * 64 + (((kt * 4 + lanehi) ^ (ra & 7)) << 3)];
      }
#pragma unroll
      for (int n = 0; n < 4; ++n) {
        const int rb = wc * 64 + n * 16 + lanelo;
        const int c0 = kt * 8 + lanehi * 2;
        const float4 f0 = *(const float4*)&Bs[rb * 64 + ((c0 ^ (rb & 7)) << 2)];
        const float4 f1 = *(const float4*)&Bs[rb * 64 + (((c0 + 1) ^ (rb & 7)) << 2)];
        union { u32 u[4]; bf16x8 v; } t;
        t.u[0] = cvtpk(f0.x, f0.y); t.u[1] = cvtpk(f0.z, f0.w);
        t.u[2] = cvtpk(f1.x, f1.y); t.u[3] = cvtpk(f1.z, f1.w);
        bf[n] = t.v;
      }
#pragma unroll
      for (int m = 0; m < 4; ++m)
#pragma unroll
        for (int n = 0; n < 4; ++n)
          acc[m][n] = __builtin_amdgcn_mfma_f32_16x16x32_bf16(af[m], bf[n], acc[m][n], 0, 0, 0);
    }
    __syncthreads();
  }
  float s = 0.f;
#pragma unroll
  for (int m = 0; m < 4; ++m)
#pragma unroll
    for (int n = 0; n < 4; ++n)
#pragma unroll
      for (int r = 0; r < 4; ++r) s += acc[m][n][r];
  scr[bid * 256 + tid] = s;
}

// ---- p0: stage+compute, BK=64, single buffer, 2 syncthreads/chunk ----
__global__ __launch_bounds__(256) void p0_base(
    const u16* __restrict__ xn, const float* __restrict__ w1, float* __restrict__ scr) {
  PDECODE
  __shared__ u16 As[128 * 64];
  __shared__ float Bs[128 * 64];
  int a_src[4], b_src[8];
#pragma unroll
  for (int j = 0; j < 4; ++j) {
    const int s = tid + 256 * j, r = s >> 3, c = s & 7;
    a_src[j] = r * DLAT + ((c ^ (r & 7)) << 3);
  }
#pragma unroll
  for (int j = 0; j < 8; ++j) {
    const int s = tid + 256 * j, r = s >> 4, c = s & 15;
    b_src[j] = r * DLAT + ((c ^ (r & 7)) << 2);
  }
  f32x4 acc[4][4] = {};
  for (int ch = 0; ch < 12; ++ch) {
    const int k2 = ch * 64;
#pragma unroll
    for (int j = 0; j < 4; ++j) gll16(Ap + a_src[j] + k2, &As[(tid + 256 * j) * 8]);
#pragma unroll
    for (int j = 0; j < 8; ++j) gll16(Bp + b_src[j] + k2, &Bs[(tid + 256 * j) * 4]);
    __syncthreads();
#pragma unroll
    for (int kt = 0; kt < 2; ++kt) {
      bf16x8 af[4], bf[4];
#pragma unroll
      for (int m = 0; m < 4; ++m) {
        const int ra = wr * 64 + m * 16 + lanelo;
        af[m] = *(const bf16x8*)&As[ra * 64 + (((kt * 4 + lanehi) ^ (ra & 7)) << 3)];
      }
#pragma unroll
      for (int n = 0; n < 4; ++n) {
        const int rb = wc * 64 + n * 16 + lanelo;
        const int c0 = kt * 8 + lanehi * 2;
        const float4 f0 = *(const float4*)&Bs[rb * 64 + ((c0 ^ (rb & 7)) << 2)];
        const float4 f1 = *(const float4*)&Bs[rb * 64 + (((c0 + 1) ^ (rb & 7)) << 2)];
        union { u32 u[4]; bf16x8 v; } t;
        t.u[0] = cvtpk(f0.x, f0.y); t.u[1] = cvtpk(f0.z, f0.w);
        t.u[2] = cvtpk(f1.x, f1.y); t.u[3] = cvtpk(f1.z, f1.w);
        bf[n] = t.v;
      }
#pragma unroll
      for (int m = 0; m < 4; ++m)
#pragma unroll
        for (int n = 0; n < 4; ++n)
          acc[m][n] = __builtin_amdgcn_mfma_f32_16x16x32_bf16(af[m], bf[n], acc[m][n], 0, 0, 0);
    }
    __syncthreads();
  }
  float s = 0.f;
#pragma unroll
  for (int m = 0; m < 4; ++m)
#pragma unroll
    for (int n = 0; n < 4; ++n)
#pragma unroll
      for (int r = 0; r < 4; ++r) s += acc[m][n][r];
  scr[bid * 256 + tid] = s;
}

// ---- p3: double-buffered BK=32 x 24 chunks, counted vmcnt(6), raw barriers ----
__global__ __launch_bounds__(256) void p3_dbuf(
    const u16* __restrict__ xn, const float* __restrict__ w1, float* __restrict__ scr) {
  PDECODE
  __shared__ u16 As[2][128 * 32];    // 8 KiB each
  __shared__ float Bs[2][128 * 32];  // 16 KiB each
  int a_src[2], b_src[4];
#pragma unroll
  for (int j = 0; j < 2; ++j) {
    const int s = tid + 256 * j, r = s >> 2, c = s & 3;
    a_src[j] = r * DLAT + ((c ^ ((r >> 1) & 3)) << 3);
  }
#pragma unroll
  for (int j = 0; j < 4; ++j) {
    const int s = tid + 256 * j, r = s >> 3, c = s & 7;
    b_src[j] = r * DLAT + ((c ^ (r & 7)) << 2);
  }
  auto stage = [&](int ch, int buf) {
    const int k2 = ch * 32;
#pragma unroll
    for (int j = 0; j < 2; ++j) gll16(Ap + a_src[j] + k2, &As[buf][(tid + 256 * j) * 8]);
#pragma unroll
    for (int j = 0; j < 4; ++j) gll16(Bp + b_src[j] + k2, &Bs[buf][(tid + 256 * j) * 4]);
  };
  f32x4 acc[4][4] = {};
  stage(0, 0);
  stage(1, 1);
  for (int ch = 0; ch < 24; ++ch) {
    if (ch < 23) asm volatile("s_waitcnt vmcnt(6)" ::: "memory");
    else         asm volatile("s_waitcnt vmcnt(0)" ::: "memory");
    __builtin_amdgcn_s_barrier();
    asm volatile("" ::: "memory");
    const int cur = ch & 1;
    {
      bf16x8 af[4], bf[4];
#pragma unroll
      for (int m = 0; m < 4; ++m) {
        const int ra = wr * 64 + m * 16 + lanelo;
        af[m] = *(const bf16x8*)&As[cur][ra * 32 + ((lanehi ^ ((ra >> 1) & 3)) << 3)];
      }
#pragma unroll
      for (int n = 0; n < 4; ++n) {
        const int rb = wc * 64 + n * 16 + lanelo;
        const float4 f0 = *(const float4*)&Bs[cur][rb * 32 + (((lanehi * 2 + 0) ^ (rb & 7)) << 2)];
        const float4 f1 = *(const float4*)&Bs[cur][rb * 32 + (((lanehi * 2 + 1) ^ (rb & 7)) << 2)];
        union { u32 u[4]; bf16x8 v; } t;
        t.u[0] = cvtpk(f0.x, f0.y); t.u[1] = cvtpk(f0.z, f0.w);
        t.u[2] = cvtpk(f1.x, f1.y); t.u[3] = cvtpk(f1.z, f1.w);
        bf[n] = t.v;
      }
#pragma unroll
      for (int m = 0; m < 4; ++m)
#pragma unroll
        for (int n = 0; n < 4; ++n)
          acc[m][n] = __builtin_amdgcn_mfma_f32_16x16x32_bf16(af[m], bf[n], acc[m][n], 0, 0, 0);
    }
    asm volatile("" ::: "memory");
    __builtin_amdgcn_s_barrier();
    asm volatile("" ::: "memory");
    if (ch + 2 < 24) stage(ch + 2, cur);
  }
  float s = 0.f;
#pragma unroll
  for (int m = 0; m < 4; ++m)
#pragma unroll
    for (int n = 0; n < 4; ++n)
#pragma unroll
      for (int r = 0; r < 4; ++r) s += acc[m][n][r];
  scr[bid * 256 + tid] = s;
}

// ---------------- fc1 (REAL, round-10 verified verbatim) ----------------
__global__ __launch_bounds__(256) void fc1_kernel(
    const u16* __restrict__ xn, const float* __restrict__ w1, u16* __restrict__ h) {
  const int bid = blockIdx.x;
  const int xcd = bid & 7;
  const int idx = bid >> 3;
  const int p = xcd * 2 + (idx >= 192 ? 1 : 0);
  const int r2 = idx % 192;
  const int nb = r2 >> 2;
  const int mb = r2 & 3;
  const int m0 = mb * 64, n0 = nb * 64;

  const int tid = threadIdx.x;
  const int lane = tid & 63, wave = tid >> 6;
  const int lanelo = lane & 15, lanehi = lane >> 4;
  const int wr = wave >> 1, wc = wave & 1;

  const u16* Ap = xn + (size_t)p * NB * DLAT + (size_t)m0 * DLAT;
  const float* Bp = w1 + (size_t)p * HDIM * DLAT + (size_t)n0 * DLAT;

  __shared__ u16 As[64 * 128];
  __shared__ float Bs[64 * 128];

  int a_src[4], b_src[8];
#pragma unroll
  for (int j = 0; j < 4; ++j) {
    const int s = tid + 256 * j;
    const int r = s >> 4, c = s & 15;
    a_src[j] = r * DLAT + ((c ^ (r & 7)) << 3);
  }
#pragma unroll
  for (int j = 0; j < 8; ++j) {
    const int s = tid + 256 * j;
    const int r = s >> 5, c = s & 31;
    b_src[j] = r * DLAT + ((c ^ (r & 7)) << 2);
  }

  const int ra0 = wr * 32 + lanelo;
  const int rb0 = wc * 32 + lanelo;

  f32x4 acc[2][2] = {};

  for (int ch = 0; ch < 6; ++ch) {
    const int k2 = ch * 128;
#pragma unroll
    for (int j = 0; j < 4; ++j)
      gll16(Ap + a_src[j] + k2, &As[(tid + 256 * j) * 8]);
#pragma unroll
    for (int j = 0; j < 8; ++j)
      gll16(Bp + b_src[j] + k2, &Bs[(tid + 256 * j) * 4]);
    __syncthreads();
#pragma unroll
    for (int kt = 0; kt < 4; ++kt) {
      bf16x8 af[2], bf[2];
#pragma unroll
      for (int m = 0; m < 2; ++m) {
        const int ra = ra0 + m * 16;
        af[m] = *(const bf16x8*)&As[ra * 128 + (((kt * 4 + lanehi) ^ (ra & 7)) << 3)];
      }
#pragma unroll
      for (int n = 0; n < 2; ++n) {
        const int rb = rb0 + n * 16;
        const float4 f0 = *(const float4*)&Bs[rb * 128 + (((kt * 8 + lanehi * 2 + 0) ^ (rb & 7)) << 2)];
        const float4 f1 = *(const float4*)&Bs[rb * 128 + (((kt * 8 + lanehi * 2 + 1) ^ (rb & 7)) << 2)];
        union { u32 u[4]; bf16x8 v; } t;
        t.u[0] = cvtpk(f0.x, f0.y);
        t.u[1] = cvtpk(f0.z, f0.w);
        t.u[2] = cvtpk(f1.x, f1.y);
        t.u[3] = cvtpk(f1.z, f1.w);
        bf[n] = t.v;
      }
#pragma unroll
      for (int m = 0; m < 2; ++m)
#pragma unroll
        for (int n = 0; n < 2; ++n)
          acc[m][n] = __builtin_amdgcn_mfma_f32_16x16x32_bf16(af[m], bf[n], acc[m][n], 0, 0, 0);
    }
    __syncthreads();
  }

  u16* hp = h + (size_t)p * NB * HDIM;
#pragma unroll
  for (int m = 0; m < 2; ++m) {
#pragma unroll
    for (int n = 0; n < 2; ++n) {
      const int col = n0 + wc * 32 + n * 16 + lanelo;
#pragma unroll
      for (int r = 0; r < 4; ++r) {
        const int row = m0 + wr * 32 + m * 16 + lanehi * 4 + r;
        const float vv = acc[m][n][r];
        const float gel = 0.5f * vv * (1.f + erff(vv * 0.70710678118654752f));
        hp[(size_t)row * HDIM + col] = f2b(gel);
      }
    }
  }
}

// ---------------- fc2: out = h @ w2^T + b2, concat slices ----------------
__global__ __launch_bounds__(256) void fc2_kernel(
    const u16* __restrict__ hbuf, const float* __restrict__ w2,
    const float* __restrict__ b2, float* __restrict__ out) {
  const int bid = blockIdx.x;
  const int bs = (bid & 7) * 32 + (bid >> 3);
  const int p = bs >> 4;
  const int mb = (bs >> 2) & 3;
  const int nb = bs & 3;
  const int odim = 100 + 10 * p;
  const int n0 = nb * 64;
  if (n0 >= odim) return;
  const int m0 = mb * 64;
  const int off = 100 * p + 5 * p * (p - 1);

  const int tid = threadIdx.x;
  const int lane = tid & 63, wave = tid >> 6;
  const int lanelo = lane & 15, lanehi = lane >> 4;
  const int wr = wave >> 1, wc = wave & 1;

  const u16* Ap = hbuf + (size_t)p * NB * HDIM + (size_t)m0 * HDIM;
  const float* Bp = w2 + (size_t)p * MAXO * HDIM;

  __shared__ u16 As[3][64 * 32];
  __shared__ u16 Bs[2][64 * 32];

  int ag_off;
  const int ag_base = (64 * wave) * 8;
  {
    int slot = 64 * wave + lane;
    int r = slot >> 2;
    int c = (slot & 3) ^ ((r >> 1) & 3);
    ag_off = r * HDIM + c * 8;
  }
  const int br0 = min(n0 + (tid >> 3), MAXO - 1);
  const int br1 = min(n0 + (tid >> 3) + 32, MAXO - 1);
  const float* bg0 = Bp + (size_t)br0 * HDIM + (tid & 7) * 4;
  const float* bg1 = Bp + (size_t)br1 * HDIM + (tid & 7) * 4;
  int bso[2];
#pragma unroll
  for (int i = 0; i < 2; ++i) {
    int r = (tid >> 3) + 32 * i;
    int c = ((tid & 7) >> 1) ^ ((r >> 1) & 3);
    bso[i] = (r * 4 + c) * 8 + (tid & 1) * 4;
  }
  int a_sl[2], b_sl[2];
#pragma unroll
  for (int m = 0; m < 2; ++m) {
    int r = wr * 32 + m * 16 + lanelo;
    a_sl[m] = (r * 4 + (lanehi ^ ((r >> 1) & 3))) * 8;
    int rb = wc * 32 + m * 16 + lanelo;
    b_sl[m] = (rb * 4 + (lanehi ^ ((rb >> 1) & 3))) * 8;
  }

  f32x4 acc[2][2] = {};
  float4 bA0, bA1, bB0, bB1;
  const int NK = HDIM / 32;

  auto issue = [&](int kt, float4& r0, float4& r1) {
    const int k2 = kt * 32;
    gll16(Ap + ag_off + k2, &As[kt % 3][ag_base]);
    asm volatile("" ::: "memory");
    r0 = *(const float4*)(bg0 + k2);
    r1 = *(const float4*)(bg1 + k2);
    asm volatile("" ::: "memory");
  };

  auto step = [&](int kt, float4& r0, float4& r1) {
    if (kt + 1 < NK) asm volatile("s_waitcnt vmcnt(3)" ::: "memory");
    else             asm volatile("s_waitcnt vmcnt(0)" ::: "memory");
    {
      u16* bb = &Bs[kt & 1][0];
      uint2 w0, w1v;
      w0.x = (u32)f2b(r0.x) | ((u32)f2b(r0.y) << 16);
      w0.y = (u32)f2b(r0.z) | ((u32)f2b(r0.w) << 16);
      w1v.x = (u32)f2b(r1.x) | ((u32)f2b(r1.y) << 16);
      w1v.y = (u32)f2b(r1.z) | ((u32)f2b(r1.w) << 16);
      *(uint2*)&bb[bso[0]] = w0;
      *(uint2*)&bb[bso[1]] = w1v;
    }
    asm volatile("s_waitcnt lgkmcnt(0)" ::: "memory");
    __builtin_amdgcn_s_barrier();
    asm volatile("" ::: "memory");
    if (kt + 2 < NK) issue(kt + 2, r0, r1);
    const u16* a_ = &As[kt % 3][0];
    const u16* b_ = &Bs[kt & 1][0];
    bf16x8 af[2], bf[2];
#pragma unroll
    for (int m = 0; m < 2; ++m) af[m] = *(const bf16x8*)&a_[a_sl[m]];
#pragma unroll
    for (int n = 0; n < 2; ++n) bf[n] = *(const bf16x8*)&b_[b_sl[n]];
#pragma unroll
    for (int m = 0; m < 2; ++m)
#pragma unroll
      for (int n = 0; n < 2; ++n)
        acc[m][n] = __builtin_amdgcn_mfma_f32_16x16x32_bf16(af[m], bf[n], acc[m][n], 0, 0, 0);
  };

  issue(0, bA0, bA1);
  issue(1, bB0, bB1);
  for (int kt = 0; kt < NK; kt += 2) {
    step(kt, bA0, bA1);
    step(kt + 1, bB0, bB1);
  }

#pragma unroll
  for (int m = 0; m < 2; ++m) {
#pragma unroll
    for (int n = 0; n < 2; ++n) {
      const int col = n0 + wc * 32 + n * 16 + lanelo;
      if (col < odim) {
        const float bias = b2[(size_t)p * MAXO + col];
#pragma unroll
        for (int r = 0; r < 4; ++r) {
          const int row = m0 + wr * 32 + m * 16 + lanehi * 4 + r;
          out[(size_t)row * TOT + off + col] = acc[m][n][r] + bias;
        }
      }
    }
  }
}

extern "C" void kernel_launch(void* const* d_in, const int* in_sizes, int n_in,
                              void* d_out, int out_size, void* d_ws, size_t ws_size,
                              hipStream_t stream) {
  const float* x = (const float*)d_in[0];
  const float* gamma = (const float*)d_in[1];
  const float* beta = (const float*)d_in[2];
  const float* w1 = (const float*)d_in[3];
  const float* w2 = (const float*)d_in[4];
  const float* b2 = (const float*)d_in[5];
  float* out = (float*)d_out;

  u16* xn = (u16*)d_ws;                             // [16][256][768] bf16
  u16* h = (u16*)d_ws + (size_t)NP * NB * DLAT;     // [16][256][3072] bf16
  float* scr = (float*)h;                           // probe scratch, overwritten by fc1

  ln_kernel<<<1024, 256, 0, stream>>>(x, gamma, beta, xn);
  // ---- ablation probes (timed via rocprof per-dispatch; h rewritten after) ----
  p1_stage<<<768, 256, 0, stream>>>(xn, w1, scr);
  p2_comp<<<768, 256, 0, stream>>>(xn, w1, scr);
  p3_dbuf<<<768, 256, 0, stream>>>(xn, w1, scr);
  p0_base<<<768, 256, 0, stream>>>(xn, w1, scr);
  // ---- real pipeline ----
  fc1_kernel<<<3072, 256, 0, stream>>>(xn, w1, h);
  fc2_kernel<<<NP * 16, 256, 0, stream>>>(h, w2, b2, out);
}

// Round 12
// 119.133 us; speedup vs baseline: 1.9243x; 1.9243x over previous
//
#include <hip/hip_runtime.h>
#include <math.h>

typedef unsigned short u16;
typedef unsigned int u32;
typedef __attribute__((ext_vector_type(4))) float f32x4;
typedef __attribute__((ext_vector_type(8))) short bf16x8;

#define NP 16
#define DLAT 768
#define HDIM 3072
#define NB 256
#define MAXO 250
#define TOT 2800

__device__ __forceinline__ u16 f2b(float f) {
  union { float f; u32 u; } v; v.f = f;
  u32 u = v.u;
  u32 r = (u + 0x7fffu + ((u >> 16) & 1u)) >> 16;
  return (u16)r;
}

__device__ __forceinline__ u32 cvtpk(float lo, float hi) {
  u32 r;
  asm("v_cvt_pk_bf16_f32 %0, %1, %2" : "=v"(r) : "v"(lo), "v"(hi));
  return r;
}

__device__ __forceinline__ void gll16(const void* g, void* l) {
  __builtin_amdgcn_global_load_lds(
      (const __attribute__((address_space(1))) void*)g,
      (__attribute__((address_space(3))) void*)l, 16, 0, 0);
}

// ---------------- LayerNorm: x[B,P,D] fp32 -> xn[P,B,D] bf16 ----------------
__global__ __launch_bounds__(256) void ln_kernel(
    const float* __restrict__ x, const float* __restrict__ gamma,
    const float* __restrict__ beta, u16* __restrict__ xn) {
  const int wave = threadIdx.x >> 6, lane = threadIdx.x & 63;
  const int row = blockIdx.x * 4 + wave;
  const int b = row >> 4, p = row & 15;
  const float4* xr = (const float4*)(x + (size_t)row * DLAT);
  const float4* g4 = (const float4*)(gamma + (size_t)p * DLAT);
  const float4* b4 = (const float4*)(beta + (size_t)p * DLAT);
  float4 v[3];
  float s = 0.f, ss = 0.f;
#pragma unroll
  for (int j = 0; j < 3; ++j) {
    v[j] = xr[lane + j * 64];
    s += v[j].x + v[j].y + v[j].z + v[j].w;
    ss += v[j].x * v[j].x + v[j].y * v[j].y + v[j].z * v[j].z + v[j].w * v[j].w;
  }
#pragma unroll
  for (int o = 32; o; o >>= 1) { s += __shfl_xor(s, o); ss += __shfl_xor(ss, o); }
  const float mu = s * (1.f / 768.f);
  const float var = ss * (1.f / 768.f) - mu * mu;
  const float rstd = rsqrtf(var + 1e-5f);
  u16* xo = xn + ((size_t)(p * NB + b)) * DLAT;
#pragma unroll
  for (int j = 0; j < 3; ++j) {
    const int f = lane + j * 64;
    float4 g = g4[f], be = b4[f];
    float o0 = (v[j].x - mu) * rstd * g.x + be.x;
    float o1 = (v[j].y - mu) * rstd * g.y + be.y;
    float o2 = (v[j].z - mu) * rstd * g.z + be.z;
    float o3 = (v[j].w - mu) * rstd * g.w + be.w;
    uint2 w;
    w.x = (u32)f2b(o0) | ((u32)f2b(o1) << 16);
    w.y = (u32)f2b(o2) | ((u32)f2b(o3) << 16);
    *(uint2*)&xo[f * 4] = w;
  }
}

// ---------------- fc1: h = GELU(xn @ w1^T)  per part ----------------
// Adopted from the p0 ablation probe (inferred ~43-47 us one-shot at 768
// blocks vs 88 us for the 64^2 shipping kernel): BM=BN=128, BK=64, 12 chunks,
// single 48 KB LDS buffer, 2 __syncthreads/chunk, 12 contiguous-row gll16
// per thread per chunk (A: 8 rows of 16B-chunks; B: full 512B w1 rows kept
// fp32, cvtpk'd after the fragment read). acc[4][4] = 32 MFMA/chunk/wave,
// 4x compute per staged byte vs the 64^2 kernel -> half the serial
// chunk-intervals. Swizzle math verified in R5/R10; epilogue verified in R5.
// XCD map: each XCD owns 2 parts; the 2 mt-siblings sharing a w1 slice are
// adjacent. Chunk-order rotation (accumulation commutes) desynchronizes the
// per-chunk memory bursts across blocks (convoy breaker).
__global__ __launch_bounds__(256) void fc1_kernel(
    const u16* __restrict__ xn, const float* __restrict__ w1, u16* __restrict__ h) {
  const int bid = blockIdx.x;              // 768 blocks
  const int xcd = bid & 7;
  const int j = bid >> 3;                  // 0..95
  const int p = xcd * 2 + (j >= 48 ? 1 : 0);
  const int jj = j % 48;                   // 24 n-tiles x 2 m-tiles
  const int n0 = (jj >> 1) * 128;
  const int m0 = (jj & 1) * 128;

  const int tid = threadIdx.x;
  const int lane = tid & 63, wave = tid >> 6;
  const int lanelo = lane & 15, lanehi = lane >> 4;
  const int wr = wave >> 1, wc = wave & 1;

  const u16* Ap = xn + (size_t)p * NB * DLAT + (size_t)m0 * DLAT;
  const float* Bp = w1 + (size_t)p * HDIM * DLAT + (size_t)n0 * DLAT;

  __shared__ u16 As[128 * 64];     // 16 KiB  [row][8 chunks of 8 bf16]
  __shared__ float Bs[128 * 64];   // 32 KiB  [row][16 chunks of 4 fp32]

  // stage sources (pre-swizzled: physical chunk c holds global chunk c^(r&7))
  int a_src[4], b_src[8];
#pragma unroll
  for (int jx = 0; jx < 4; ++jx) {
    const int s = tid + 256 * jx, r = s >> 3, c = s & 7;
    a_src[jx] = r * DLAT + ((c ^ (r & 7)) << 3);       // u16 elems
  }
#pragma unroll
  for (int jx = 0; jx < 8; ++jx) {
    const int s = tid + 256 * jx, r = s >> 4, c = s & 15;
    b_src[jx] = r * DLAT + ((c ^ (r & 7)) << 2);       // floats
  }

  f32x4 acc[4][4] = {};
  const int st = bid % 12;                 // chunk rotation offset

  for (int cc = 0; cc < 12; ++cc) {
    const int ch = (cc + st) % 12;
    const int k2 = ch * 64;
    // ---- stage chunk: 12 gll16/thread, all contiguous full-row segments ----
#pragma unroll
    for (int jx = 0; jx < 4; ++jx)
      gll16(Ap + a_src[jx] + k2, &As[(tid + 256 * jx) * 8]);
#pragma unroll
    for (int jx = 0; jx < 8; ++jx)
      gll16(Bp + b_src[jx] + k2, &Bs[(tid + 256 * jx) * 4]);
    __syncthreads();
    // ---- compute 2 K-steps (32 MFMA/wave) from LDS ----
#pragma unroll
    for (int kt = 0; kt < 2; ++kt) {
      bf16x8 af[4], bf[4];
#pragma unroll
      for (int m = 0; m < 4; ++m) {
        const int ra = wr * 64 + m * 16 + lanelo;
        af[m] = *(const bf16x8*)&As[ra * 64 + (((kt * 4 + lanehi) ^ (ra & 7)) << 3)];
      }
#pragma unroll
      for (int n = 0; n < 4; ++n) {
        const int rb = wc * 64 + n * 16 + lanelo;
        const int c0 = kt * 8 + lanehi * 2;
        const float4 f0 = *(const float4*)&Bs[rb * 64 + ((c0 ^ (rb & 7)) << 2)];
        const float4 f1 = *(const float4*)&Bs[rb * 64 + (((c0 + 1) ^ (rb & 7)) << 2)];
        union { u32 u[4]; bf16x8 v; } t;
        t.u[0] = cvtpk(f0.x, f0.y); t.u[1] = cvtpk(f0.z, f0.w);
        t.u[2] = cvtpk(f1.x, f1.y); t.u[3] = cvtpk(f1.z, f1.w);
        bf[n] = t.v;
      }
#pragma unroll
      for (int m = 0; m < 4; ++m)
#pragma unroll
        for (int n = 0; n < 4; ++n)
          acc[m][n] = __builtin_amdgcn_mfma_f32_16x16x32_bf16(af[m], bf[n], acc[m][n], 0, 0, 0);
    }
    __syncthreads();
  }

  // epilogue: exact GELU, store bf16 (R5-verified mapping)
  u16* hp = h + (size_t)p * NB * HDIM;
#pragma unroll
  for (int m = 0; m < 4; ++m) {
#pragma unroll
    for (int n = 0; n < 4; ++n) {
      const int col = n0 + wc * 64 + n * 16 + lanelo;
#pragma unroll
      for (int r = 0; r < 4; ++r) {
        const int row = m0 + wr * 64 + m * 16 + lanehi * 4 + r;
        const float vv = acc[m][n][r];
        const float gel = 0.5f * vv * (1.f + erff(vv * 0.70710678118654752f));
        hp[(size_t)row * HDIM + col] = f2b(gel);
      }
    }
  }
}

// ---------------- fc2: out = h @ w2^T + b2, concat slices ----------------
// BM=64, BN=64, BK=32; 4 waves 2x2, each 32x32. (validated, ~memory floor)
__global__ __launch_bounds__(256) void fc2_kernel(
    const u16* __restrict__ hbuf, const float* __restrict__ w2,
    const float* __restrict__ b2, float* __restrict__ out) {
  const int bid = blockIdx.x;
  const int bs = (bid & 7) * 32 + (bid >> 3);    // XCD swizzle (256 = 8*32)
  const int p = bs >> 4;
  const int mb = (bs >> 2) & 3;
  const int nb = bs & 3;
  const int odim = 100 + 10 * p;
  const int n0 = nb * 64;
  if (n0 >= odim) return;                        // uniform per block
  const int m0 = mb * 64;
  const int off = 100 * p + 5 * p * (p - 1);

  const int tid = threadIdx.x;
  const int lane = tid & 63, wave = tid >> 6;
  const int lanelo = lane & 15, lanehi = lane >> 4;
  const int wr = wave >> 1, wc = wave & 1;

  const u16* Ap = hbuf + (size_t)p * NB * HDIM + (size_t)m0 * HDIM;
  const float* Bp = w2 + (size_t)p * MAXO * HDIM;

  __shared__ u16 As[3][64 * 32];   // 12 KiB
  __shared__ u16 Bs[2][64 * 32];   // 8 KiB

  int ag_off;
  const int ag_base = (64 * wave) * 8;
  {
    int slot = 64 * wave + lane;
    int r = slot >> 2;
    int c = (slot & 3) ^ ((r >> 1) & 3);
    ag_off = r * HDIM + c * 8;
  }
  const int br0 = min(n0 + (tid >> 3), MAXO - 1);
  const int br1 = min(n0 + (tid >> 3) + 32, MAXO - 1);
  const float* bg0 = Bp + (size_t)br0 * HDIM + (tid & 7) * 4;
  const float* bg1 = Bp + (size_t)br1 * HDIM + (tid & 7) * 4;
  int bso[2];
#pragma unroll
  for (int i = 0; i < 2; ++i) {
    int r = (tid >> 3) + 32 * i;
    int c = ((tid & 7) >> 1) ^ ((r >> 1) & 3);
    bso[i] = (r * 4 + c) * 8 + (tid & 1) * 4;
  }
  int a_sl[2], b_sl[2];
#pragma unroll
  for (int m = 0; m < 2; ++m) {
    int r = wr * 32 + m * 16 + lanelo;
    a_sl[m] = (r * 4 + (lanehi ^ ((r >> 1) & 3))) * 8;
    int rb = wc * 32 + m * 16 + lanelo;
    b_sl[m] = (rb * 4 + (lanehi ^ ((rb >> 1) & 3))) * 8;
  }

  f32x4 acc[2][2] = {};
  float4 bA0, bA1, bB0, bB1;
  const int NK = HDIM / 32;  // 96

  auto issue = [&](int kt, float4& r0, float4& r1) {
    const int k2 = kt * 32;
    gll16(Ap + ag_off + k2, &As[kt % 3][ag_base]);
    asm volatile("" ::: "memory");
    r0 = *(const float4*)(bg0 + k2);
    r1 = *(const float4*)(bg1 + k2);
    asm volatile("" ::: "memory");
  };

  auto step = [&](int kt, float4& r0, float4& r1) {
    if (kt + 1 < NK) asm volatile("s_waitcnt vmcnt(3)" ::: "memory");
    else             asm volatile("s_waitcnt vmcnt(0)" ::: "memory");
    {
      u16* bb = &Bs[kt & 1][0];
      uint2 w0, w1v;
      w0.x = (u32)f2b(r0.x) | ((u32)f2b(r0.y) << 16);
      w0.y = (u32)f2b(r0.z) | ((u32)f2b(r0.w) << 16);
      w1v.x = (u32)f2b(r1.x) | ((u32)f2b(r1.y) << 16);
      w1v.y = (u32)f2b(r1.z) | ((u32)f2b(r1.w) << 16);
      *(uint2*)&bb[bso[0]] = w0;
      *(uint2*)&bb[bso[1]] = w1v;
    }
    asm volatile("s_waitcnt lgkmcnt(0)" ::: "memory");
    __builtin_amdgcn_s_barrier();
    asm volatile("" ::: "memory");
    if (kt + 2 < NK) issue(kt + 2, r0, r1);
    const u16* a_ = &As[kt % 3][0];
    const u16* b_ = &Bs[kt & 1][0];
    bf16x8 af[2], bf[2];
#pragma unroll
    for (int m = 0; m < 2; ++m) af[m] = *(const bf16x8*)&a_[a_sl[m]];
#pragma unroll
    for (int n = 0; n < 2; ++n) bf[n] = *(const bf16x8*)&b_[b_sl[n]];
#pragma unroll
    for (int m = 0; m < 2; ++m)
#pragma unroll
      for (int n = 0; n < 2; ++n)
        acc[m][n] = __builtin_amdgcn_mfma_f32_16x16x32_bf16(af[m], bf[n], acc[m][n], 0, 0, 0);
  };

  issue(0, bA0, bA1);
  issue(1, bB0, bB1);
  for (int kt = 0; kt < NK; kt += 2) {
    step(kt, bA0, bA1);
    step(kt + 1, bB0, bB1);
  }

#pragma unroll
  for (int m = 0; m < 2; ++m) {
#pragma unroll
    for (int n = 0; n < 2; ++n) {
      const int col = n0 + wc * 32 + n * 16 + lanelo;
      if (col < odim) {
        const float bias = b2[(size_t)p * MAXO + col];
#pragma unroll
        for (int r = 0; r < 4; ++r) {
          const int row = m0 + wr * 32 + m * 16 + lanehi * 4 + r;
          out[(size_t)row * TOT + off + col] = acc[m][n][r] + bias;
        }
      }
    }
  }
}

extern "C" void kernel_launch(void* const* d_in, const int* in_sizes, int n_in,
                              void* d_out, int out_size, void* d_ws, size_t ws_size,
                              hipStream_t stream) {
  const float* x = (const float*)d_in[0];
  const float* gamma = (const float*)d_in[1];
  const float* beta = (const float*)d_in[2];
  const float* w1 = (const float*)d_in[3];
  const float* w2 = (const float*)d_in[4];
  const float* b2 = (const float*)d_in[5];
  float* out = (float*)d_out;

  u16* xn = (u16*)d_ws;                             // [16][256][768] bf16
  u16* h = (u16*)d_ws + (size_t)NP * NB * DLAT;     // [16][256][3072] bf16

  ln_kernel<<<1024, 256, 0, stream>>>(x, gamma, beta, xn);
  fc1_kernel<<<768, 256, 0, stream>>>(xn, w1, h);
  fc2_kernel<<<NP * 16, 256, 0, stream>>>(h, w2, b2, out);
}

// Round 13
// 104.810 us; speedup vs baseline: 2.1872x; 1.1367x over previous
//
#include <hip/hip_runtime.h>
#include <math.h>

typedef unsigned short u16;
typedef unsigned int u32;
typedef __attribute__((ext_vector_type(4))) float f32x4;
typedef __attribute__((ext_vector_type(8))) short bf16x8;

#define NP 16
#define DLAT 768
#define HDIM 3072
#define NB 256
#define MAXO 250
#define TOT 2800

__device__ __forceinline__ u16 f2b(float f) {
  union { float f; u32 u; } v; v.f = f;
  u32 u = v.u;
  u32 r = (u + 0x7fffu + ((u >> 16) & 1u)) >> 16;
  return (u16)r;
}

__device__ __forceinline__ u32 cvtpk(float lo, float hi) {
  u32 r;
  asm("v_cvt_pk_bf16_f32 %0, %1, %2" : "=v"(r) : "v"(lo), "v"(hi));
  return r;
}

__device__ __forceinline__ void gll16(const void* g, void* l) {
  __builtin_amdgcn_global_load_lds(
      (const __attribute__((address_space(1))) void*)g,
      (__attribute__((address_space(3))) void*)l, 16, 0, 0);
}

// ---------------- LayerNorm: x[B,P,D] fp32 -> xn[P,B,D] bf16 ----------------
__global__ __launch_bounds__(256) void ln_kernel(
    const float* __restrict__ x, const float* __restrict__ gamma,
    const float* __restrict__ beta, u16* __restrict__ xn) {
  const int wave = threadIdx.x >> 6, lane = threadIdx.x & 63;
  const int row = blockIdx.x * 4 + wave;
  const int b = row >> 4, p = row & 15;
  const float4* xr = (const float4*)(x + (size_t)row * DLAT);
  const float4* g4 = (const float4*)(gamma + (size_t)p * DLAT);
  const float4* b4 = (const float4*)(beta + (size_t)p * DLAT);
  float4 v[3];
  float s = 0.f, ss = 0.f;
#pragma unroll
  for (int j = 0; j < 3; ++j) {
    v[j] = xr[lane + j * 64];
    s += v[j].x + v[j].y + v[j].z + v[j].w;
    ss += v[j].x * v[j].x + v[j].y * v[j].y + v[j].z * v[j].z + v[j].w * v[j].w;
  }
#pragma unroll
  for (int o = 32; o; o >>= 1) { s += __shfl_xor(s, o); ss += __shfl_xor(ss, o); }
  const float mu = s * (1.f / 768.f);
  const float var = ss * (1.f / 768.f) - mu * mu;
  const float rstd = rsqrtf(var + 1e-5f);
  u16* xo = xn + ((size_t)(p * NB + b)) * DLAT;
#pragma unroll
  for (int j = 0; j < 3; ++j) {
    const int f = lane + j * 64;
    float4 g = g4[f], be = b4[f];
    float o0 = (v[j].x - mu) * rstd * g.x + be.x;
    float o1 = (v[j].y - mu) * rstd * g.y + be.y;
    float o2 = (v[j].z - mu) * rstd * g.z + be.z;
    float o3 = (v[j].w - mu) * rstd * g.w + be.w;
    uint2 w;
    w.x = (u32)f2b(o0) | ((u32)f2b(o1) << 16);
    w.y = (u32)f2b(o2) | ((u32)f2b(o3) << 16);
    *(uint2*)&xo[f * 4] = w;
  }
}

// ---------------- fc1: h = GELU(xn @ w1^T)  per part ----------------
// R11 p3 probe structure promoted to the real kernel: 128x128 tile, BK=32 x
// 24 steps, 2-deep LDS double buffer, counted s_waitcnt vmcnt(6) (loads stay
// in flight across barriers; drains to 0 only in the tail). 6 gll16 per
// thread per stage (A bf16 2, B fp32 4), 16 MFMA/wave/step. Each wave drains
// ITS OWN glls via vmcnt before the barrier; the barrier then makes the whole
// buffer visible to all waves (guide's verified wait discipline).
// Swizzle pair + epilogue mapping = R5-verified; XCD decode = R5/R10-verified
// (mt-siblings of each (p,n0) adjacent on one XCD -> w1 L2-dedup, FETCH~79MB).
__global__ __launch_bounds__(256) void fc1_kernel(
    const u16* __restrict__ xn, const float* __restrict__ w1, u16* __restrict__ h) {
  const int bid = blockIdx.x;              // 768 blocks
  const int xcd = bid & 7;
  const int j = bid >> 3;                  // 0..95 within XCD
  const int p = xcd * 2 + (j >= 48 ? 1 : 0);
  const int jj = j % 48;                   // 24 n-tiles x 2 m-tiles
  const int n0 = (jj >> 1) * 128;
  const int m0 = (jj & 1) * 128;

  const int tid = threadIdx.x;
  const int lane = tid & 63, wave = tid >> 6;
  const int lanelo = lane & 15, lanehi = lane >> 4;
  const int wr = wave >> 1, wc = wave & 1;

  const u16* Ap = xn + (size_t)p * NB * DLAT + (size_t)m0 * DLAT;
  const float* Bp = w1 + (size_t)p * HDIM * DLAT + (size_t)n0 * DLAT;

  __shared__ u16 As[2][128 * 32];    // 8 KiB each  [row][4 chunks of 8 bf16]
  __shared__ float Bs[2][128 * 32];  // 16 KiB each [row][8 chunks of 4 fp32]

  // stage sources (pre-swizzled): A chunk c of row r lands at c^((r>>1)&3);
  // B chunk c of row r lands at c^(r&7). LDS destinations stay linear (gll).
  int a_src[2], b_src[4];
#pragma unroll
  for (int jx = 0; jx < 2; ++jx) {
    const int s = tid + 256 * jx, r = s >> 2, c = s & 3;
    a_src[jx] = r * DLAT + ((c ^ ((r >> 1) & 3)) << 3);   // u16 elems
  }
#pragma unroll
  for (int jx = 0; jx < 4; ++jx) {
    const int s = tid + 256 * jx, r = s >> 3, c = s & 7;
    b_src[jx] = r * DLAT + ((c ^ (r & 7)) << 2);          // floats
  }

  auto stage = [&](int ch, int buf) {
    const int k2 = ch * 32;
#pragma unroll
    for (int jx = 0; jx < 2; ++jx)
      gll16(Ap + a_src[jx] + k2, &As[buf][(tid + 256 * jx) * 8]);
#pragma unroll
    for (int jx = 0; jx < 4; ++jx)
      gll16(Bp + b_src[jx] + k2, &Bs[buf][(tid + 256 * jx) * 4]);
  };

  f32x4 acc[4][4] = {};
  stage(0, 0);
  stage(1, 1);

  for (int ch = 0; ch < 24; ++ch) {
    if (ch < 23) asm volatile("s_waitcnt vmcnt(6)" ::: "memory");
    else         asm volatile("s_waitcnt vmcnt(0)" ::: "memory");
    __builtin_amdgcn_s_barrier();
    asm volatile("" ::: "memory");
    const int cur = ch & 1;
    {
      bf16x8 af[4], bf[4];
#pragma unroll
      for (int m = 0; m < 4; ++m) {
        const int ra = wr * 64 + m * 16 + lanelo;
        af[m] = *(const bf16x8*)&As[cur][ra * 32 + ((lanehi ^ ((ra >> 1) & 3)) << 3)];
      }
#pragma unroll
      for (int n = 0; n < 4; ++n) {
        const int rb = wc * 64 + n * 16 + lanelo;
        const float4 f0 = *(const float4*)&Bs[cur][rb * 32 + (((lanehi * 2 + 0) ^ (rb & 7)) << 2)];
        const float4 f1 = *(const float4*)&Bs[cur][rb * 32 + (((lanehi * 2 + 1) ^ (rb & 7)) << 2)];
        union { u32 u[4]; bf16x8 v; } t;
        t.u[0] = cvtpk(f0.x, f0.y); t.u[1] = cvtpk(f0.z, f0.w);
        t.u[2] = cvtpk(f1.x, f1.y); t.u[3] = cvtpk(f1.z, f1.w);
        bf[n] = t.v;
      }
#pragma unroll
      for (int m = 0; m < 4; ++m)
#pragma unroll
        for (int n = 0; n < 4; ++n)
          acc[m][n] = __builtin_amdgcn_mfma_f32_16x16x32_bf16(af[m], bf[n], acc[m][n], 0, 0, 0);
    }
    asm volatile("" ::: "memory");
    __builtin_amdgcn_s_barrier();
    asm volatile("" ::: "memory");
    if (ch + 2 < 24) stage(ch + 2, cur);   // refill the buffer just consumed
  }

  // epilogue: exact GELU, store bf16 (R5-verified mapping)
  u16* hp = h + (size_t)p * NB * HDIM;
#pragma unroll
  for (int m = 0; m < 4; ++m) {
#pragma unroll
    for (int n = 0; n < 4; ++n) {
      const int col = n0 + wc * 64 + n * 16 + lanelo;
#pragma unroll
      for (int r = 0; r < 4; ++r) {
        const int row = m0 + wr * 64 + m * 16 + lanehi * 4 + r;
        const float vv = acc[m][n][r];
        const float gel = 0.5f * vv * (1.f + erff(vv * 0.70710678118654752f));
        hp[(size_t)row * HDIM + col] = f2b(gel);
      }
    }
  }
}

// ---------------- fc2: out = h @ w2^T + b2, concat slices ----------------
// BM=64, BN=64, BK=32; 4 waves 2x2, each 32x32. (validated, ~memory floor)
__global__ __launch_bounds__(256) void fc2_kernel(
    const u16* __restrict__ hbuf, const float* __restrict__ w2,
    const float* __restrict__ b2, float* __restrict__ out) {
  const int bid = blockIdx.x;
  const int bs = (bid & 7) * 32 + (bid >> 3);    // XCD swizzle (256 = 8*32)
  const int p = bs >> 4;
  const int mb = (bs >> 2) & 3;
  const int nb = bs & 3;
  const int odim = 100 + 10 * p;
  const int n0 = nb * 64;
  if (n0 >= odim) return;                        // uniform per block
  const int m0 = mb * 64;
  const int off = 100 * p + 5 * p * (p - 1);

  const int tid = threadIdx.x;
  const int lane = tid & 63, wave = tid >> 6;
  const int lanelo = lane & 15, lanehi = lane >> 4;
  const int wr = wave >> 1, wc = wave & 1;

  const u16* Ap = hbuf + (size_t)p * NB * HDIM + (size_t)m0 * HDIM;
  const float* Bp = w2 + (size_t)p * MAXO * HDIM;

  __shared__ u16 As[3][64 * 32];   // 12 KiB
  __shared__ u16 Bs[2][64 * 32];   // 8 KiB

  int ag_off;
  const int ag_base = (64 * wave) * 8;
  {
    int slot = 64 * wave + lane;
    int r = slot >> 2;
    int c = (slot & 3) ^ ((r >> 1) & 3);
    ag_off = r * HDIM + c * 8;
  }
  const int br0 = min(n0 + (tid >> 3), MAXO - 1);
  const int br1 = min(n0 + (tid >> 3) + 32, MAXO - 1);
  const float* bg0 = Bp + (size_t)br0 * HDIM + (tid & 7) * 4;
  const float* bg1 = Bp + (size_t)br1 * HDIM + (tid & 7) * 4;
  int bso[2];
#pragma unroll
  for (int i = 0; i < 2; ++i) {
    int r = (tid >> 3) + 32 * i;
    int c = ((tid & 7) >> 1) ^ ((r >> 1) & 3);
    bso[i] = (r * 4 + c) * 8 + (tid & 1) * 4;
  }
  int a_sl[2], b_sl[2];
#pragma unroll
  for (int m = 0; m < 2; ++m) {
    int r = wr * 32 + m * 16 + lanelo;
    a_sl[m] = (r * 4 + (lanehi ^ ((r >> 1) & 3))) * 8;
    int rb = wc * 32 + m * 16 + lanelo;
    b_sl[m] = (rb * 4 + (lanehi ^ ((rb >> 1) & 3))) * 8;
  }

  f32x4 acc[2][2] = {};
  float4 bA0, bA1, bB0, bB1;
  const int NK = HDIM / 32;  // 96

  auto issue = [&](int kt, float4& r0, float4& r1) {
    const int k2 = kt * 32;
    gll16(Ap + ag_off + k2, &As[kt % 3][ag_base]);
    asm volatile("" ::: "memory");
    r0 = *(const float4*)(bg0 + k2);
    r1 = *(const float4*)(bg1 + k2);
    asm volatile("" ::: "memory");
  };

  auto step = [&](int kt, float4& r0, float4& r1) {
    if (kt + 1 < NK) asm volatile("s_waitcnt vmcnt(3)" ::: "memory");
    else             asm volatile("s_waitcnt vmcnt(0)" ::: "memory");
    {
      u16* bb = &Bs[kt & 1][0];
      uint2 w0, w1v;
      w0.x = (u32)f2b(r0.x) | ((u32)f2b(r0.y) << 16);
      w0.y = (u32)f2b(r0.z) | ((u32)f2b(r0.w) << 16);
      w1v.x = (u32)f2b(r1.x) | ((u32)f2b(r1.y) << 16);
      w1v.y = (u32)f2b(r1.z) | ((u32)f2b(r1.w) << 16);
      *(uint2*)&bb[bso[0]] = w0;
      *(uint2*)&bb[bso[1]] = w1v;
    }
    asm volatile("s_waitcnt lgkmcnt(0)" ::: "memory");
    __builtin_amdgcn_s_barrier();
    asm volatile("" ::: "memory");
    if (kt + 2 < NK) issue(kt + 2, r0, r1);
    const u16* a_ = &As[kt % 3][0];
    const u16* b_ = &Bs[kt & 1][0];
    bf16x8 af[2], bf[2];
#pragma unroll
    for (int m = 0; m < 2; ++m) af[m] = *(const bf16x8*)&a_[a_sl[m]];
#pragma unroll
    for (int n = 0; n < 2; ++n) bf[n] = *(const bf16x8*)&b_[b_sl[n]];
#pragma unroll
    for (int m = 0; m < 2; ++m)
#pragma unroll
      for (int n = 0; n < 2; ++n)
        acc[m][n] = __builtin_amdgcn_mfma_f32_16x16x32_bf16(af[m], bf[n], acc[m][n], 0, 0, 0);
  };

  issue(0, bA0, bA1);
  issue(1, bB0, bB1);
  for (int kt = 0; kt < NK; kt += 2) {
    step(kt, bA0, bA1);
    step(kt + 1, bB0, bB1);
  }

#pragma unroll
  for (int m = 0; m < 2; ++m) {
#pragma unroll
    for (int n = 0; n < 2; ++n) {
      const int col = n0 + wc * 32 + n * 16 + lanelo;
      if (col < odim) {
        const float bias = b2[(size_t)p * MAXO + col];
#pragma unroll
        for (int r = 0; r < 4; ++r) {
          const int row = m0 + wr * 32 + m * 16 + lanehi * 4 + r;
          out[(size_t)row * TOT + off + col] = acc[m][n][r] + bias;
        }
      }
    }
  }
}

extern "C" void kernel_launch(void* const* d_in, const int* in_sizes, int n_in,
                              void* d_out, int out_size, void* d_ws, size_t ws_size,
                              hipStream_t stream) {
  const float* x = (const float*)d_in[0];
  const float* gamma = (const float*)d_in[1];
  const float* beta = (const float*)d_in[2];
  const float* w1 = (const float*)d_in[3];
  const float* w2 = (const float*)d_in[4];
  const float* b2 = (const float*)d_in[5];
  float* out = (float*)d_out;

  u16* xn = (u16*)d_ws;                             // [16][256][768] bf16
  u16* h = (u16*)d_ws + (size_t)NP * NB * DLAT;     // [16][256][3072] bf16

  ln_kernel<<<1024, 256, 0, stream>>>(x, gamma, beta, xn);
  fc1_kernel<<<768, 256, 0, stream>>>(xn, w1, h);
  fc2_kernel<<<NP * 16, 256, 0, stream>>>(h, w2, b2, out);
}